// Round 1
// 360.333 us; speedup vs baseline: 1.1330x; 1.1330x over previous
//
#include <hip/hip_runtime.h>
#include <hip/hip_bf16.h>

#define D_     256
#define TWO_DI 1024
#define DI_    512
#define NSTATE 16
#define RR     16
#define NDBL   48      // R + 2N
#define BSEQ   8
#define NC     256
#define NCHUNK 16
#define CLEN   16
#define CTX    2048    // 8*256
#define TGT    512     // 8*64

typedef __attribute__((ext_vector_type(8))) short short8v;
typedef __attribute__((ext_vector_type(8))) unsigned short ushort8v;
typedef __attribute__((ext_vector_type(4))) float floatx4;

__device__ __forceinline__ float siluf(float x) { return x / (1.f + __expf(-x)); }
__device__ __forceinline__ float softplusf(float x) {
  return fmaxf(x, 0.f) + log1pf(__expf(-fabsf(x)));
}
__device__ __forceinline__ unsigned short f2bf(float x) {
  unsigned u = __float_as_uint(x);
  u += 0x7fffu + ((u >> 16) & 1u);          // round-to-nearest-even
  return (unsigned short)(u >> 16);
}
__device__ __forceinline__ float bf2f(unsigned short b) {
  return __uint_as_float((unsigned)b << 16);
}

// ---- one-shot prep: W_in/W_o/W_x transpose->bf16 + Aneg = -exp(A_log) ----
__global__ __launch_bounds__(256) void prep_all(
    const float* __restrict__ W_in, const float* __restrict__ W_o,
    const float* __restrict__ W_x, const float* __restrict__ Alog,
    unsigned short* __restrict__ Wint, unsigned short* __restrict__ Wot,
    unsigned short* __restrict__ Wxt, float* __restrict__ Aneg)
{
  __shared__ float tile[32][33];
  int b = blockIdx.x;
  const float* src; unsigned short* dst; int R, C, cx, ry;
  if (b < 1024) {          // W_in: 4 x [256][1024] -> [1024][256]
    int z = b >> 8, t = b & 255; cx = t & 31; ry = t >> 5; R = 256; C = 1024;
    src = W_in + (size_t)z * R * C; dst = Wint + (size_t)z * R * C;
  } else if (b < 1536) {   // W_o: 4 x [512][256] -> [256][512]
    int bb = b - 1024; int z = bb >> 7, t = bb & 127; cx = t & 7; ry = t >> 3; R = 512; C = 256;
    src = W_o + (size_t)z * R * C; dst = Wot + (size_t)z * R * C;
  } else if (b < 1664) {   // W_x: 4 x [512][48] -> [48][512]
    int bb = b - 1536; int z = bb >> 5, t = bb & 31; cx = t & 1; ry = t >> 1; R = 512; C = 48;
    src = W_x + (size_t)z * R * C; dst = Wxt + (size_t)z * R * C;
  } else {                 // Aneg
    int i = (b - 1664) * 256 + threadIdx.x;
    if (i < 4 * DI_ * NSTATE) Aneg[i] = -__expf(Alog[i]);
    return;
  }
  int c0 = cx * 32, r0 = ry * 32;
  int tx = threadIdx.x & 31, ty = threadIdx.x >> 5;
#pragma unroll
  for (int i = 0; i < 4; ++i) {
    int r = r0 + ty + i * 8;
    tile[ty + i * 8][tx] = (r < R && c0 + tx < C) ? src[(size_t)r * C + c0 + tx] : 0.f;
  }
  __syncthreads();
#pragma unroll
  for (int i = 0; i < 4; ++i) {
    int c = c0 + ty + i * 8;
    if (c < C && r0 + tx < R)
      dst[(size_t)c * R + r0 + tx] = f2bf(tile[tx][ty + i * 8]);
  }
}

// ---------------- LayerNorm -> bf16 rows (GEMM A operand) ----------------
__device__ __forceinline__ void ln_body(int bx, const float* __restrict__ x,
    const float* __restrict__ g, const float* __restrict__ be,
    unsigned short* __restrict__ out, int rows)
{
  int wid = threadIdx.x >> 6, lane = threadIdx.x & 63;
  int row = bx * 4 + wid;
  if (row >= rows) return;
  const float4 v = *reinterpret_cast<const float4*>(&x[(size_t)row * D_ + lane * 4]);
  float s  = v.x + v.y + v.z + v.w;
  float sq = v.x * v.x + v.y * v.y + v.z * v.z + v.w * v.w;
#pragma unroll
  for (int off = 32; off; off >>= 1) {
    s  += __shfl_xor(s, off);
    sq += __shfl_xor(sq, off);
  }
  float mu   = s * (1.f / D_);
  float var  = sq * (1.f / D_) - mu * mu;
  float rstd = rsqrtf(var + 1e-5f);
  const float4 gv = *reinterpret_cast<const float4*>(&g[lane * 4]);
  const float4 bv = *reinterpret_cast<const float4*>(&be[lane * 4]);
  ushort4 o;
  o.x = f2bf((v.x - mu) * rstd * gv.x + bv.x);
  o.y = f2bf((v.y - mu) * rstd * gv.y + bv.y);
  o.z = f2bf((v.z - mu) * rstd * gv.z + bv.z);
  o.w = f2bf((v.w - mu) * rstd * gv.w + bv.w);
  *reinterpret_cast<ushort4*>(&out[(size_t)row * D_ + lane * 4]) = o;
}

__global__ __launch_bounds__(256) void ln_kern(const float* __restrict__ x,
    const float* __restrict__ g, const float* __restrict__ be,
    unsigned short* __restrict__ out, int rows)
{
  ln_body(blockIdx.x, x, g, be, out, rows);
}

// fused: LN for phase-A layer (CTX rows) + LN for phase-B layer (TGT rows)
__global__ __launch_bounds__(256) void fused_ln(
    const float* __restrict__ xA, const float* __restrict__ gA,
    const float* __restrict__ bA, unsigned short* __restrict__ oA,
    const float* __restrict__ xB, const float* __restrict__ gB,
    const float* __restrict__ bB, unsigned short* __restrict__ oB)
{
  if (blockIdx.x < CTX / 4) ln_body(blockIdx.x, xA, gA, bA, oA, CTX);
  else                      ln_body(blockIdx.x - CTX / 4, xB, gB, bB, oB, TGT);
}

// ------- MFMA bf16 GEMM, 64x64 tile, register double-buffered K loop.
// EPI=0: [+resid]->C.  EPI=1 (tgt in-proj): col<512 -> silu(cconv+v*w3)->xcv_bf; else zbuf. -------
template<int EPI>
__device__ __forceinline__ void gemm_body(
    unsigned short (*As)[72], unsigned short (*Bs)[72], int bx, int by,
    const unsigned short* __restrict__ A, const unsigned short* __restrict__ Bt,
    const float* __restrict__ resid, float* __restrict__ C, int M, int N, int K,
    const float* __restrict__ cconv, const float* __restrict__ Wc4,
    unsigned short* __restrict__ xcv_bf, float* __restrict__ zbuf)
{
  int tid = threadIdx.x;
  int n0 = bx * 64, m0 = by * 64;
  int w = tid >> 6, lane = tid & 63;
  int lr = lane & 15, kq = lane >> 4;
  int wr = w >> 1, wc = w & 1;
  int srow = tid >> 2, schunk = (tid & 3) * 16;
  const unsigned short* Ap = &A[(size_t)(m0 + srow) * K + schunk];
  const unsigned short* Bp = &Bt[(size_t)(n0 + srow) * K + schunk];
  ushort8v a0 = *reinterpret_cast<const ushort8v*>(Ap);
  ushort8v a1 = *reinterpret_cast<const ushort8v*>(Ap + 8);
  ushort8v b0 = *reinterpret_cast<const ushort8v*>(Bp);
  ushort8v b1 = *reinterpret_cast<const ushort8v*>(Bp + 8);
  floatx4 acc[2][2] = {};
  for (int k0 = 0; k0 < K; k0 += 64) {
    __syncthreads();
    *reinterpret_cast<ushort8v*>(&As[srow][schunk])     = a0;
    *reinterpret_cast<ushort8v*>(&As[srow][schunk + 8]) = a1;
    *reinterpret_cast<ushort8v*>(&Bs[srow][schunk])     = b0;
    *reinterpret_cast<ushort8v*>(&Bs[srow][schunk + 8]) = b1;
    __syncthreads();
    if (k0 + 64 < K) {   // prefetch next K tile; latency hides under MFMA
      a0 = *reinterpret_cast<const ushort8v*>(Ap + k0 + 64);
      a1 = *reinterpret_cast<const ushort8v*>(Ap + k0 + 72);
      b0 = *reinterpret_cast<const ushort8v*>(Bp + k0 + 64);
      b1 = *reinterpret_cast<const ushort8v*>(Bp + k0 + 72);
    }
#pragma unroll
    for (int ks = 0; ks < 2; ++ks) {
      short8v af[2], bf2v[2];
#pragma unroll
      for (int f = 0; f < 2; ++f)
        af[f] = *reinterpret_cast<const short8v*>(&As[wr * 32 + f * 16 + lr][ks * 32 + kq * 8]);
#pragma unroll
      for (int g2 = 0; g2 < 2; ++g2)
        bf2v[g2] = *reinterpret_cast<const short8v*>(&Bs[wc * 32 + g2 * 16 + lr][ks * 32 + kq * 8]);
#pragma unroll
      for (int f = 0; f < 2; ++f)
#pragma unroll
        for (int g2 = 0; g2 < 2; ++g2)
          acc[f][g2] = __builtin_amdgcn_mfma_f32_16x16x32_bf16(af[f], bf2v[g2], acc[f][g2], 0, 0, 0);
    }
  }
#pragma unroll
  for (int f = 0; f < 2; ++f)
#pragma unroll
    for (int g2 = 0; g2 < 2; ++g2) {
      int col = n0 + wc * 32 + g2 * 16 + lr;
#pragma unroll
      for (int r = 0; r < 4; ++r) {
        int row = m0 + wr * 32 + f * 16 + kq * 4 + r;
        float v = acc[f][g2][r];
        if (EPI == 0) {
          if (resid) v += resid[(size_t)row * N + col];
          C[(size_t)row * N + col] = v;
        } else {
          int b = row >> 6;
          if (col < DI_) {
            float sv = siluf(cconv[b * DI_ + col] + v * Wc4[col * 4 + 3]);
            xcv_bf[(size_t)row * DI_ + col] = f2bf(sv);
          } else {
            zbuf[(size_t)row * DI_ + (col - DI_)] = v;
          }
        }
      }
    }
}

template<int EPI>
__global__ __launch_bounds__(256) void gemm_bf16(
    const unsigned short* __restrict__ A, const unsigned short* __restrict__ Bt,
    const float* __restrict__ resid, float* __restrict__ C, int M, int N, int K,
    const float* __restrict__ cconv, const float* __restrict__ Wc4,
    unsigned short* __restrict__ xcv_bf, float* __restrict__ zbuf)
{
  __shared__ unsigned short As[64][72];
  __shared__ unsigned short Bs[64][72];
  gemm_body<EPI>(As, Bs, blockIdx.x, blockIdx.y, A, Bt, resid, C, M, N, K,
                 cconv, Wc4, xcv_bf, zbuf);
}

// fused: phase-A in-proj (512 blocks, 16x32) + phase-B in-proj EPI=1 (128 blocks, 16x8)
__global__ __launch_bounds__(256) void fused_gemm_in(
    const unsigned short* __restrict__ Aa, const unsigned short* __restrict__ Bta,
    float* __restrict__ Ca,
    const unsigned short* __restrict__ Ab, const unsigned short* __restrict__ Btb,
    const float* __restrict__ cconv, const float* __restrict__ Wc4,
    unsigned short* __restrict__ xcv_bf, float* __restrict__ zbuf)
{
  __shared__ unsigned short As[64][72];
  __shared__ unsigned short Bs[64][72];
  int f = blockIdx.x;
  if (f < 512)
    gemm_body<0>(As, Bs, f & 15, f >> 4, Aa, Bta, nullptr, Ca, CTX, TWO_DI, D_,
                 nullptr, nullptr, nullptr, nullptr);
  else {
    f -= 512;
    gemm_body<1>(As, Bs, f & 15, f >> 4, Ab, Btb, nullptr, nullptr, TGT, TWO_DI, D_,
                 cconv, Wc4, xcv_bf, zbuf);
  }
}

// ------- small-tile MFMA GEMM: 32x32 tile, 128 blocks for M=512,N=256 (tgt out-proj) -------
__device__ __forceinline__ void gemm_s_body(int bx, int by,
    const unsigned short* __restrict__ A, const unsigned short* __restrict__ Bt,
    const float* __restrict__ resid, float* __restrict__ C, int M, int N, int K)
{
  __shared__ unsigned short As[32][72];
  __shared__ unsigned short Bs[32][72];
  int tid = threadIdx.x;
  int n0 = bx * 32, m0 = by * 32;
  int w = tid >> 6, lane = tid & 63;
  int lr = lane & 15, kq = lane >> 4;
  int wr = w >> 1, wc = w & 1;
  int srow = tid >> 3, schunk = (tid & 7) * 8;
  const unsigned short* Ap = &A[(size_t)(m0 + srow) * K + schunk];
  const unsigned short* Bp = &Bt[(size_t)(n0 + srow) * K + schunk];
  ushort8v a0 = *reinterpret_cast<const ushort8v*>(Ap);
  ushort8v b0 = *reinterpret_cast<const ushort8v*>(Bp);
  floatx4 acc = {};
  for (int k0 = 0; k0 < K; k0 += 64) {
    __syncthreads();
    *reinterpret_cast<ushort8v*>(&As[srow][schunk]) = a0;
    *reinterpret_cast<ushort8v*>(&Bs[srow][schunk]) = b0;
    __syncthreads();
    if (k0 + 64 < K) {
      a0 = *reinterpret_cast<const ushort8v*>(Ap + k0 + 64);
      b0 = *reinterpret_cast<const ushort8v*>(Bp + k0 + 64);
    }
#pragma unroll
    for (int ks = 0; ks < 2; ++ks) {
      short8v af = *reinterpret_cast<const short8v*>(&As[wr * 16 + lr][ks * 32 + kq * 8]);
      short8v bf = *reinterpret_cast<const short8v*>(&Bs[wc * 16 + lr][ks * 32 + kq * 8]);
      acc = __builtin_amdgcn_mfma_f32_16x16x32_bf16(af, bf, acc, 0, 0, 0);
    }
  }
  int col = n0 + wc * 16 + lr;
#pragma unroll
  for (int r = 0; r < 4; ++r) {
    int row = m0 + wr * 16 + kq * 4 + r;
    float v = acc[r];
    if (resid) v += resid[(size_t)row * N + col];
    C[(size_t)row * N + col] = v;
  }
}

__global__ __launch_bounds__(256) void gemm_s(
    const unsigned short* __restrict__ A, const unsigned short* __restrict__ Bt,
    const float* __restrict__ resid, float* __restrict__ C, int M, int N, int K)
{
  gemm_s_body(blockIdx.x, blockIdx.y, A, Bt, resid, C, M, N, K);
}

// ===== fused ctx: conv+silu -> dbl (MFMA) -> dt -> chunk-local scan (S,P) =====
// 128 block-ids = seq*16+chunk; 16 tokens/block.
__device__ __forceinline__ void conv_body(int blk,
    const float* __restrict__ xz, const float* __restrict__ Wc,
    const float* __restrict__ bc, const unsigned short* __restrict__ Wxt,
    const float* __restrict__ Wdt, const float* __restrict__ bdt,
    const float* __restrict__ Aneg,
    unsigned short* __restrict__ xcvb, float* __restrict__ dtb,
    float* __restrict__ dblg, float* __restrict__ cconv,
    float* __restrict__ Sb, float* __restrict__ Pb)
{
  __shared__ unsigned short xcs[16][528];
  __shared__ float dts_s[16][520];
  __shared__ float dbl_s[16][48];
  int seq = blk >> 4, ch = blk & 15;
  int tok0 = blk * 16;
  int tid = threadIdx.x;
  // ---- conv + silu ----
#pragma unroll
  for (int hh = 0; hh < 2; ++hh) {
    int c = tid + hh * 256;
    float w0 = Wc[c * 4 + 0], w1 = Wc[c * 4 + 1], w2 = Wc[c * 4 + 2], w3 = Wc[c * 4 + 3];
    float bcv = bc[c];
    const float* xzs = &xz[(size_t)(seq * NC) * TWO_DI + c];
    for (int t = 0; t < 16; ++t) {
      int tl = ch * 16 + t;
      float acc = bcv + xzs[(size_t)tl * TWO_DI] * w3;
      if (tl >= 1) acc += xzs[(size_t)(tl - 1) * TWO_DI] * w2;
      if (tl >= 2) acc += xzs[(size_t)(tl - 2) * TWO_DI] * w1;
      if (tl >= 3) acc += xzs[(size_t)(tl - 3) * TWO_DI] * w0;
      unsigned short sv = f2bf(siluf(acc));
      xcs[t][c] = sv;
      xcvb[(size_t)(tok0 + t) * DI_ + c] = sv;
    }
    if (ch == 15)   // conv constant for this batch's 64 decode steps
      cconv[seq * DI_ + c] = bcv + xzs[(size_t)253 * TWO_DI] * w0
                                 + xzs[(size_t)254 * TWO_DI] * w1
                                 + xzs[(size_t)255 * TWO_DI] * w2;
  }
  __syncthreads();
  // ---- dbl[16][48] = xcv @ Wx^T via MFMA (3 waves) ----
  int w = tid >> 6, lane = tid & 63, lr = lane & 15, kq = lane >> 4;
  if (w < 3) {
    floatx4 acc = {};
#pragma unroll
    for (int kc = 0; kc < 16; ++kc) {
      short8v bb = *reinterpret_cast<const short8v*>(&Wxt[(size_t)(w * 16 + lr) * DI_ + kc * 32 + kq * 8]);
      short8v aa = *reinterpret_cast<const short8v*>(&xcs[lr][kc * 32 + kq * 8]);
      acc = __builtin_amdgcn_mfma_f32_16x16x32_bf16(aa, bb, acc, 0, 0, 0);
    }
#pragma unroll
    for (int r = 0; r < 4; ++r) {
      int t = kq * 4 + r, col = w * 16 + lr;
      dbl_s[t][col] = acc[r];
      dblg[(size_t)(tok0 + t) * NDBL + col] = acc[r];
    }
  }
  __syncthreads();
  // ---- dt = softplus(dbl[:, :16] @ Wdt + bdt) ----
#pragma unroll
  for (int hh = 0; hh < 2; ++hh) {
    int c = tid + hh * 256;
    float wr_[16];
#pragma unroll
    for (int r = 0; r < 16; ++r) wr_[r] = Wdt[r * DI_ + c];
    float bv = bdt[c];
    for (int t = 0; t < 16; ++t) {
      float accd = bv;
#pragma unroll
      for (int r = 0; r < 16; ++r) accd += dbl_s[t][r] * wr_[r];
      float dtv = softplusf(accd);
      dts_s[t][c] = dtv;
      dtb[(size_t)(tok0 + t) * DI_ + c] = dtv;
    }
  }
  __syncthreads();
  // ---- chunk-local scan from h=0: emit (S, P) per (d, n) ----
  int dl = tid >> 4, n = tid & 15;
  float Bt_r[16];                       // B[t][n] invariant over dg -> registers
#pragma unroll
  for (int t = 0; t < 16; ++t) Bt_r[t] = dbl_s[t][RR + n];
  for (int dg = 0; dg < 32; ++dg) {
    int d = dg * 16 + dl;
    float A = Aneg[d * NSTATE + n];
    float h = 0.f, p = 1.f;
#pragma unroll
    for (int t = 0; t < 16; ++t) {
      float dtv = dts_s[t][d];
      float xv  = bf2f(xcs[t][d]);
      float dA  = __expf(dtv * A);
      h = fmaf(dA, h, dtv * xv * Bt_r[t]);
      p *= dA;
    }
    size_t o = ((size_t)blk * DI_ + d) * NSTATE + n;
    Sb[o] = h; Pb[o] = p;
  }
}

__global__ __launch_bounds__(256) void conv_dbl_part(
    const float* __restrict__ xz, const float* __restrict__ Wc,
    const float* __restrict__ bc, const unsigned short* __restrict__ Wxt,
    const float* __restrict__ Wdt, const float* __restrict__ bdt,
    const float* __restrict__ Aneg,
    unsigned short* __restrict__ xcvb, float* __restrict__ dtb,
    float* __restrict__ dblg, float* __restrict__ cconv,
    float* __restrict__ Sb, float* __restrict__ Pb)
{
  conv_body(blockIdx.x, xz, Wc, bc, Wxt, Wdt, bdt, Aneg, xcvb, dtb, dblg, cconv, Sb, Pb);
}

// ---- scan finalize: prefix-combine entry state, re-scan chunk, C-reduce + gate ----
__device__ __forceinline__ void sf_body(int b,
    const float* __restrict__ dblg, const unsigned short* __restrict__ xcvb,
    const float* __restrict__ xz, const float* __restrict__ dtb,
    const float* __restrict__ Sb, const float* __restrict__ Pb,
    const float* __restrict__ Aneg, const float* __restrict__ Dp,
    unsigned short* __restrict__ yb, float* __restrict__ hstate)
{
  int dg = b & 31, sc = b >> 5;
  int seq = sc >> 4, chunk = sc & 15;
  int tid = threadIdx.x;
  int tt = tid >> 4, cc = tid & 15;
  int tok0 = sc * CLEN;
  __shared__ float dts[16][17], xs[16][17], zs[16][17], Bs[16][17], Cs[16][17], ys[16][17];
  dts[tt][cc] = dtb[(size_t)(tok0 + tt) * DI_ + dg * 16 + cc];
  xs[tt][cc]  = bf2f(xcvb[(size_t)(tok0 + tt) * DI_ + dg * 16 + cc]);
  zs[tt][cc]  = xz[(size_t)(tok0 + tt) * TWO_DI + DI_ + dg * 16 + cc];
  Bs[tt][cc]  = dblg[(size_t)(tok0 + tt) * NDBL + RR + cc];
  Cs[tt][cc]  = dblg[(size_t)(tok0 + tt) * NDBL + RR + NSTATE + cc];
  __syncthreads();
  int dl = tt, n = cc;
  int d = dg * 16 + dl;
  float A  = Aneg[d * NSTATE + n];
  float Dv = Dp[d];
  float Bn[16], Cn[16];                 // B/C rows for this thread's n -> registers
#pragma unroll
  for (int t = 0; t < CLEN; ++t) { Bn[t] = Bs[t][n]; Cn[t] = Cs[t][n]; }
  float h = 0.f;
  for (int c2 = 0; c2 < chunk; ++c2) {
    size_t o = ((size_t)(seq * NCHUNK + c2) * DI_ + d) * NSTATE + n;
    h = fmaf(Pb[o], h, Sb[o]);
  }
#pragma unroll
  for (int t = 0; t < CLEN; ++t) {
    float dtv = dts[t][dl];
    float xv  = xs[t][dl];
    float dA  = __expf(dtv * A);
    h = fmaf(dA, h, dtv * xv * Bn[t]);
    float p = h * Cn[t];
    p += __shfl_xor(p, 1); p += __shfl_xor(p, 2);
    p += __shfl_xor(p, 4); p += __shfl_xor(p, 8);
    if (n == 0) ys[t][dl] = (p + xv * Dv) * siluf(zs[t][dl]);
  }
  __syncthreads();
  yb[(size_t)(tok0 + tt) * DI_ + dg * 16 + cc] = f2bf(ys[tt][cc]);
  if (chunk == NCHUNK - 1)
    hstate[(size_t)seq * DI_ * NSTATE + d * NSTATE + n] = h;
}

__global__ __launch_bounds__(256) void scan_fin(
    const float* __restrict__ dblg, const unsigned short* __restrict__ xcvb,
    const float* __restrict__ xz, const float* __restrict__ dtb,
    const float* __restrict__ Sb, const float* __restrict__ Pb,
    const float* __restrict__ Aneg, const float* __restrict__ Dp,
    unsigned short* __restrict__ yb, float* __restrict__ hstate)
{
  sf_body(blockIdx.x, dblg, xcvb, xz, dtb, Sb, Pb, Aneg, Dp, yb, hstate);
}

// ---- target SSM, 256 block-ids = (32 token-groups) x (8 ch-groups of 64). ----
__device__ __forceinline__ void ssm_body(int blk,
    const unsigned short* __restrict__ xcv_bf, const float* __restrict__ zbuf,
    const unsigned short* __restrict__ Wx, const float* __restrict__ Wdt_l,
    const float* __restrict__ bdt_l, const float* __restrict__ An_l,
    const float* __restrict__ Dp_l, const float* __restrict__ hs,
    unsigned short* __restrict__ ybf)
{
  __shared__ float dbl_s[16][48];
  int tg = blk >> 3, cg = blk & 7;
  int tok0 = tg * 16;
  int b = tg >> 2;                      // batch (64 tokens each)
  int tid = threadIdx.x;
  int w = tid >> 6, lane = tid & 63, lr = lane & 15, kq = lane >> 4;
  if (w < 3) {
    floatx4 acc = {};
#pragma unroll
    for (int kc = 0; kc < 16; ++kc) {
      short8v bb = *reinterpret_cast<const short8v*>(&Wx[(size_t)(w * 16 + lr) * DI_ + kc * 32 + kq * 8]);
      short8v aa = *reinterpret_cast<const short8v*>(&xcv_bf[(size_t)(tok0 + lr) * DI_ + kc * 32 + kq * 8]);
      acc = __builtin_amdgcn_mfma_f32_16x16x32_bf16(aa, bb, acc, 0, 0, 0);
    }
#pragma unroll
    for (int r = 0; r < 4; ++r)
      dbl_s[kq * 4 + r][w * 16 + lr] = acc[r];
  }
  __syncthreads();
  int c = cg * 64 + (tid & 63);
  int t0 = (tid >> 6) * 4;              // 4 tokens per thread
  float wdt_r[16], An[16], hr[16];
#pragma unroll
  for (int r = 0; r < 16; ++r) wdt_r[r] = Wdt_l[r * DI_ + c];
  const float4* An4 = reinterpret_cast<const float4*>(&An_l[c * NSTATE]);
  const float4* hr4 = reinterpret_cast<const float4*>(&hs[(size_t)b * DI_ * NSTATE + c * NSTATE]);
#pragma unroll
  for (int q = 0; q < 4; ++q) {
    float4 a = An4[q]; An[q*4]=a.x; An[q*4+1]=a.y; An[q*4+2]=a.z; An[q*4+3]=a.w;
    float4 hv = hr4[q]; hr[q*4]=hv.x; hr[q*4+1]=hv.y; hr[q*4+2]=hv.z; hr[q*4+3]=hv.w;
  }
  float Dv = Dp_l[c], bv = bdt_l[c];
#pragma unroll
  for (int tt = 0; tt < 4; ++tt) {
    int t = t0 + tt;
    float accd = bv;
#pragma unroll
    for (int r = 0; r < 16; ++r) accd += dbl_s[t][r] * wdt_r[r];
    float dtv = softplusf(accd);
    float xv = bf2f(xcv_bf[(size_t)(tok0 + t) * DI_ + c]);
    float coef = dtv * xv;
    float y = 0.f;
#pragma unroll
    for (int n = 0; n < 16; ++n) {
      float hn = fmaf(__expf(dtv * An[n]), hr[n], coef * dbl_s[t][RR + n]);
      y = fmaf(hn, dbl_s[t][RR + NSTATE + n], y);
    }
    float yv = (y + xv * Dv) * siluf(zbuf[(size_t)(tok0 + t) * DI_ + c]);
    ybf[(size_t)(tok0 + t) * DI_ + c] = f2bf(yv);
  }
}

__global__ __launch_bounds__(256) void tgt_ssm2(
    const unsigned short* __restrict__ xcv_bf, const float* __restrict__ zbuf,
    const unsigned short* __restrict__ Wx, const float* __restrict__ Wdt_l,
    const float* __restrict__ bdt_l, const float* __restrict__ An_l,
    const float* __restrict__ Dp_l, const float* __restrict__ hs,
    unsigned short* __restrict__ ybf)
{
  ssm_body(blockIdx.x, xcv_bf, zbuf, Wx, Wdt_l, bdt_l, An_l, Dp_l, hs, ybf);
}

// fused: conv/scan-part for A layer (128 blocks) + tgt SSM for B layer (256 blocks)
__global__ __launch_bounds__(256) void fused_conv_ssm(
    const float* __restrict__ xz, const float* __restrict__ Wc,
    const float* __restrict__ bc, const unsigned short* __restrict__ WxtA,
    const float* __restrict__ WdtA, const float* __restrict__ bdtA,
    const float* __restrict__ AnegA,
    unsigned short* __restrict__ xcvb, float* __restrict__ dtb,
    float* __restrict__ dblg, float* __restrict__ cconv,
    float* __restrict__ Sb, float* __restrict__ Pb,
    const unsigned short* __restrict__ xcv_bfB, const float* __restrict__ zbufB,
    const unsigned short* __restrict__ WxB, const float* __restrict__ WdtB,
    const float* __restrict__ bdtB, const float* __restrict__ AnB,
    const float* __restrict__ DpB, const float* __restrict__ hsB,
    unsigned short* __restrict__ ybfB)
{
  if (blockIdx.x < BSEQ * NCHUNK)
    conv_body(blockIdx.x, xz, Wc, bc, WxtA, WdtA, bdtA, AnegA,
              xcvb, dtb, dblg, cconv, Sb, Pb);
  else
    ssm_body(blockIdx.x - BSEQ * NCHUNK, xcv_bfB, zbufB, WxB, WdtB, bdtB,
             AnB, DpB, hsB, ybfB);
}

// fused: B out-proj gemm_s (128 blocks, dispatched first) + A scan_fin (4096 blocks)
__global__ __launch_bounds__(256) void fused_sf_gout(
    const unsigned short* __restrict__ Ag, const unsigned short* __restrict__ Btg,
    const float* __restrict__ residg, float* __restrict__ Cg,
    const float* __restrict__ dblg, const unsigned short* __restrict__ xcvb,
    const float* __restrict__ xz, const float* __restrict__ dtb,
    const float* __restrict__ Sb, const float* __restrict__ Pb,
    const float* __restrict__ Aneg, const float* __restrict__ Dp,
    unsigned short* __restrict__ yb, float* __restrict__ hstate)
{
  if (blockIdx.x < 128) {
    int f = blockIdx.x;
    gemm_s_body(f & 7, f >> 3, Ag, Btg, residg, Cg, TGT, D_, DI_);
  } else {
    sf_body(blockIdx.x - 128, dblg, xcvb, xz, dtb, Sb, Pb, Aneg, Dp, yb, hstate);
  }
}

extern "C" void kernel_launch(void* const* d_in, const int* in_sizes, int n_in,
                              void* d_out, int out_size, void* d_ws, size_t ws_size,
                              hipStream_t stream)
{
  const float* xc   = (const float*)d_in[0];
  const float* xt   = (const float*)d_in[1];
  const float* ln_g = (const float*)d_in[2];
  const float* ln_b = (const float*)d_in[3];
  const float* W_in = (const float*)d_in[4];
  const float* W_cv = (const float*)d_in[5];
  const float* b_cv = (const float*)d_in[6];
  const float* W_x  = (const float*)d_in[7];
  const float* W_dt = (const float*)d_in[8];
  const float* b_dt = (const float*)d_in[9];
  const float* Alog = (const float*)d_in[10];
  const float* Dp   = (const float*)d_in[11];
  const float* W_o  = (const float*)d_in[12];
  float* out = (float*)d_out;

  float* ws = (float*)d_ws;
  size_t off = 0;
  auto alloc = [&](size_t n) { float* p = ws + off; off += n; return p; };
  float* xz     = alloc((size_t)CTX * TWO_DI);
  float* dtb    = alloc((size_t)CTX * DI_);
  float* dblg   = alloc((size_t)CTX * NDBL);
  float* xcur   = alloc((size_t)CTX * D_);
  float* Sb     = alloc((size_t)BSEQ * NCHUNK * DI_ * NSTATE);
  float* Pb     = alloc((size_t)BSEQ * NCHUNK * DI_ * NSTATE);
  float* cconvT = alloc((size_t)4 * BSEQ * DI_);
  float* hst    = alloc((size_t)4 * BSEQ * DI_ * NSTATE);
  float* Aneg   = alloc((size_t)4 * DI_ * NSTATE);
  float* zbufB  = alloc((size_t)TGT * DI_);
  float* xtb    = alloc((size_t)TGT * D_);
  unsigned short* hbuf_bf = (unsigned short*)alloc((size_t)CTX * D_ / 2);
  unsigned short* hbufB   = (unsigned short*)alloc((size_t)TGT * D_ / 2);
  unsigned short* xcvb    = (unsigned short*)alloc((size_t)CTX * DI_ / 2);
  unsigned short* yb_bf   = (unsigned short*)alloc((size_t)CTX * DI_ / 2);
  unsigned short* xcv_bfB = (unsigned short*)alloc((size_t)TGT * DI_ / 2);
  unsigned short* y_bfB   = (unsigned short*)alloc((size_t)TGT * DI_ / 2);
  unsigned short* Wint    = (unsigned short*)alloc((size_t)4 * TWO_DI * D_ / 2);
  unsigned short* Wot     = (unsigned short*)alloc((size_t)4 * D_ * DI_ / 2);
  unsigned short* Wxt     = (unsigned short*)alloc((size_t)4 * NDBL * DI_ / 2);
  if (off * sizeof(float) > ws_size) return;

  prep_all<<<1792, 256, 0, stream>>>(W_in, W_o, W_x, Alog, Wint, Wot, Wxt, Aneg);

  // -------- A0 (no B partner yet) --------
  ln_kern<<<CTX / 4, 256, 0, stream>>>(xc, ln_g, ln_b, hbuf_bf, CTX);
  gemm_bf16<0><<<dim3(TWO_DI / 64, CTX / 64), 256, 0, stream>>>(
      hbuf_bf, Wint, nullptr, xz, CTX, TWO_DI, D_, nullptr, nullptr, nullptr, nullptr);
  conv_dbl_part<<<BSEQ * NCHUNK, 256, 0, stream>>>(
      xz, W_cv, b_cv, Wxt, W_dt, b_dt, Aneg, xcvb, dtb, dblg, cconvT, Sb, Pb);
  scan_fin<<<BSEQ * NCHUNK * 32, 256, 0, stream>>>(
      dblg, xcvb, xz, dtb, Sb, Pb, Aneg, Dp, yb_bf, hst);
  gemm_bf16<0><<<dim3(D_ / 64, CTX / 64), 256, 0, stream>>>(
      yb_bf, Wot, xc, xcur, CTX, D_, DI_, nullptr, nullptr, nullptr, nullptr);

  // -------- groups: A(l+1) co-scheduled with B(l) --------
  for (int l = 0; l < 3; ++l) {
    int la = l + 1;
    const float* xinB = (l == 0) ? xt : xtb;
    fused_ln<<<CTX / 4 + TGT / 4, 256, 0, stream>>>(
        xcur, ln_g + la * D_, ln_b + la * D_, hbuf_bf,
        xinB, ln_g + l * D_,  ln_b + l * D_,  hbufB);
    fused_gemm_in<<<512 + 128, 256, 0, stream>>>(
        hbuf_bf, Wint + (size_t)la * TWO_DI * D_, xz,
        hbufB,   Wint + (size_t)l * TWO_DI * D_,
        cconvT + (size_t)l * BSEQ * DI_, W_cv + l * DI_ * 4, xcv_bfB, zbufB);
    fused_conv_ssm<<<BSEQ * NCHUNK + 256, 256, 0, stream>>>(
        xz, W_cv + la * DI_ * 4, b_cv + la * DI_, Wxt + (size_t)la * NDBL * DI_,
        W_dt + la * RR * DI_, b_dt + la * DI_, Aneg + la * DI_ * NSTATE,
        xcvb, dtb, dblg, cconvT + (size_t)la * BSEQ * DI_, Sb, Pb,
        xcv_bfB, zbufB, Wxt + (size_t)l * NDBL * DI_, W_dt + l * RR * DI_,
        b_dt + l * DI_, Aneg + l * DI_ * NSTATE, Dp + l * DI_,
        hst + (size_t)l * BSEQ * DI_ * NSTATE, y_bfB);
    fused_sf_gout<<<128 + BSEQ * NCHUNK * 32, 256, 0, stream>>>(
        y_bfB, Wot + (size_t)l * D_ * DI_, xinB, xtb,
        dblg, xcvb, xz, dtb, Sb, Pb, Aneg + la * DI_ * NSTATE, Dp + la * DI_,
        yb_bf, hst + (size_t)la * BSEQ * DI_ * NSTATE);
    if (la < 3)
      gemm_bf16<0><<<dim3(D_ / 64, CTX / 64), 256, 0, stream>>>(
          yb_bf, Wot + (size_t)la * D_ * DI_, xcur, xcur, CTX, D_, DI_,
          nullptr, nullptr, nullptr, nullptr);
  }

  // -------- B3 tail --------
  ln_kern<<<TGT / 4, 256, 0, stream>>>(xtb, ln_g + 3 * D_, ln_b + 3 * D_, hbufB, TGT);
  gemm_bf16<1><<<dim3(TWO_DI / 64, TGT / 64), 256, 0, stream>>>(
      hbufB, Wint + (size_t)3 * TWO_DI * D_, nullptr, nullptr, TGT, TWO_DI, D_,
      cconvT + (size_t)3 * BSEQ * DI_, W_cv + 3 * DI_ * 4, xcv_bfB, zbufB);
  tgt_ssm2<<<256, 256, 0, stream>>>(xcv_bfB, zbufB,
      Wxt + (size_t)3 * NDBL * DI_, W_dt + 3 * RR * DI_, b_dt + 3 * DI_,
      Aneg + 3 * DI_ * NSTATE, Dp + 3 * DI_,
      hst + (size_t)3 * BSEQ * DI_ * NSTATE, y_bfB);
  gemm_s<<<dim3(D_ / 32, TGT / 32), 256, 0, stream>>>(
      y_bfB, Wot + (size_t)3 * D_ * DI_, xtb, out, TGT, D_, DI_);
}

// Round 2
// 306.320 us; speedup vs baseline: 1.3328x; 1.1763x over previous
//
#include <hip/hip_runtime.h>
#include <hip/hip_bf16.h>

#define D_     256
#define TWO_DI 1024
#define DI_    512
#define NSTATE 16
#define RR     16
#define NDBL   48      // R + 2N
#define BSEQ   8
#define NC     256
#define NCHUNK 16
#define CLEN   16
#define CTX    2048    // 8*256
#define TGT    512     // 8*64

typedef __attribute__((ext_vector_type(8))) short short8v;
typedef __attribute__((ext_vector_type(8))) unsigned short ushort8v;
typedef __attribute__((ext_vector_type(4))) float floatx4;

__device__ __forceinline__ float siluf(float x) { return x / (1.f + __expf(-x)); }
__device__ __forceinline__ float softplusf(float x) {
  return fmaxf(x, 0.f) + log1pf(__expf(-fabsf(x)));
}
__device__ __forceinline__ unsigned short f2bf(float x) {
  unsigned u = __float_as_uint(x);
  u += 0x7fffu + ((u >> 16) & 1u);          // round-to-nearest-even
  return (unsigned short)(u >> 16);
}
__device__ __forceinline__ float bf2f(unsigned short b) {
  return __uint_as_float((unsigned)b << 16);
}

// ---- one-shot prep: W_in/W_o/W_x transpose->bf16, WdtT transpose, Aneg ----
__global__ __launch_bounds__(256) void prep_all(
    const float* __restrict__ W_in, const float* __restrict__ W_o,
    const float* __restrict__ W_x, const float* __restrict__ Alog,
    const float* __restrict__ W_dt,
    unsigned short* __restrict__ Wint, unsigned short* __restrict__ Wot,
    unsigned short* __restrict__ Wxt, float* __restrict__ Aneg,
    float* __restrict__ WdtT)
{
  __shared__ float tile[32][33];
  int b = blockIdx.x;
  const float* src; unsigned short* dst; int R, C, cx, ry;
  if (b < 1024) {          // W_in: 4 x [256][1024] -> [1024][256]
    int z = b >> 8, t = b & 255; cx = t & 31; ry = t >> 5; R = 256; C = 1024;
    src = W_in + (size_t)z * R * C; dst = Wint + (size_t)z * R * C;
  } else if (b < 1536) {   // W_o: 4 x [512][256] -> [256][512]
    int bb = b - 1024; int z = bb >> 7, t = bb & 127; cx = t & 7; ry = t >> 3; R = 512; C = 256;
    src = W_o + (size_t)z * R * C; dst = Wot + (size_t)z * R * C;
  } else if (b < 1664) {   // W_x: 4 x [512][48] -> [48][512]
    int bb = b - 1536; int z = bb >> 5, t = bb & 31; cx = t & 1; ry = t >> 1; R = 512; C = 48;
    src = W_x + (size_t)z * R * C; dst = Wxt + (size_t)z * R * C;
  } else if (b < 1792) {   // Aneg
    int i = (b - 1664) * 256 + threadIdx.x;
    if (i < 4 * DI_ * NSTATE) Aneg[i] = -__expf(Alog[i]);
    return;
  } else {                 // WdtT: 4 x [16][512] -> [512][16]
    int i = (b - 1792) * 256 + threadIdx.x;   // 32768 total
    int z = i >> 13, rem = i & 8191, c = rem >> 4, r = rem & 15;
    WdtT[i] = W_dt[(size_t)z * RR * DI_ + r * DI_ + c];
    return;
  }
  int c0 = cx * 32, r0 = ry * 32;
  int tx = threadIdx.x & 31, ty = threadIdx.x >> 5;
#pragma unroll
  for (int i = 0; i < 4; ++i) {
    int r = r0 + ty + i * 8;
    tile[ty + i * 8][tx] = (r < R && c0 + tx < C) ? src[(size_t)r * C + c0 + tx] : 0.f;
  }
  __syncthreads();
#pragma unroll
  for (int i = 0; i < 4; ++i) {
    int c = c0 + ty + i * 8;
    if (c < C && r0 + tx < R)
      dst[(size_t)c * R + r0 + tx] = f2bf(tile[tx][ty + i * 8]);
  }
}

// ---------------- LayerNorm -> bf16 rows (GEMM A operand) ----------------
__device__ __forceinline__ void ln_body(int bx, const float* __restrict__ x,
    const float* __restrict__ g, const float* __restrict__ be,
    unsigned short* __restrict__ out, int rows)
{
  int wid = threadIdx.x >> 6, lane = threadIdx.x & 63;
  int row = bx * 4 + wid;
  if (row >= rows) return;
  const float4 v = *reinterpret_cast<const float4*>(&x[(size_t)row * D_ + lane * 4]);
  float s  = v.x + v.y + v.z + v.w;
  float sq = v.x * v.x + v.y * v.y + v.z * v.z + v.w * v.w;
#pragma unroll
  for (int off = 32; off; off >>= 1) {
    s  += __shfl_xor(s, off);
    sq += __shfl_xor(sq, off);
  }
  float mu   = s * (1.f / D_);
  float var  = sq * (1.f / D_) - mu * mu;
  float rstd = rsqrtf(var + 1e-5f);
  const float4 gv = *reinterpret_cast<const float4*>(&g[lane * 4]);
  const float4 bv = *reinterpret_cast<const float4*>(&be[lane * 4]);
  ushort4 o;
  o.x = f2bf((v.x - mu) * rstd * gv.x + bv.x);
  o.y = f2bf((v.y - mu) * rstd * gv.y + bv.y);
  o.z = f2bf((v.z - mu) * rstd * gv.z + bv.z);
  o.w = f2bf((v.w - mu) * rstd * gv.w + bv.w);
  *reinterpret_cast<ushort4*>(&out[(size_t)row * D_ + lane * 4]) = o;
}

__global__ __launch_bounds__(256) void ln_kern(const float* __restrict__ x,
    const float* __restrict__ g, const float* __restrict__ be,
    unsigned short* __restrict__ out, int rows)
{
  ln_body(blockIdx.x, x, g, be, out, rows);
}

// fused: LN for phase-A layer (CTX rows) + LN for phase-B layer (TGT rows)
__global__ __launch_bounds__(256) void fused_ln(
    const float* __restrict__ xA, const float* __restrict__ gA,
    const float* __restrict__ bA, unsigned short* __restrict__ oA,
    const float* __restrict__ xB, const float* __restrict__ gB,
    const float* __restrict__ bB, unsigned short* __restrict__ oB)
{
  if (blockIdx.x < CTX / 4) ln_body(blockIdx.x, xA, gA, bA, oA, CTX);
  else                      ln_body(blockIdx.x - CTX / 4, xB, gB, bB, oB, TGT);
}

// ------- MFMA bf16 GEMM, 64x64 tile, register double-buffered K loop. -------
template<int EPI>
__device__ __forceinline__ void gemm_body(
    unsigned short (*As)[72], unsigned short (*Bs)[72], int bx, int by,
    const unsigned short* __restrict__ A, const unsigned short* __restrict__ Bt,
    const float* __restrict__ resid, float* __restrict__ C, int M, int N, int K,
    const float* __restrict__ cconv, const float* __restrict__ Wc4,
    unsigned short* __restrict__ xcv_bf, float* __restrict__ zbuf)
{
  int tid = threadIdx.x;
  int n0 = bx * 64, m0 = by * 64;
  int w = tid >> 6, lane = tid & 63;
  int lr = lane & 15, kq = lane >> 4;
  int wr = w >> 1, wc = w & 1;
  int srow = tid >> 2, schunk = (tid & 3) * 16;
  const unsigned short* Ap = &A[(size_t)(m0 + srow) * K + schunk];
  const unsigned short* Bp = &Bt[(size_t)(n0 + srow) * K + schunk];
  ushort8v a0 = *reinterpret_cast<const ushort8v*>(Ap);
  ushort8v a1 = *reinterpret_cast<const ushort8v*>(Ap + 8);
  ushort8v b0 = *reinterpret_cast<const ushort8v*>(Bp);
  ushort8v b1 = *reinterpret_cast<const ushort8v*>(Bp + 8);
  floatx4 acc[2][2] = {};
  for (int k0 = 0; k0 < K; k0 += 64) {
    __syncthreads();
    *reinterpret_cast<ushort8v*>(&As[srow][schunk])     = a0;
    *reinterpret_cast<ushort8v*>(&As[srow][schunk + 8]) = a1;
    *reinterpret_cast<ushort8v*>(&Bs[srow][schunk])     = b0;
    *reinterpret_cast<ushort8v*>(&Bs[srow][schunk + 8]) = b1;
    __syncthreads();
    if (k0 + 64 < K) {   // prefetch next K tile; latency hides under MFMA
      a0 = *reinterpret_cast<const ushort8v*>(Ap + k0 + 64);
      a1 = *reinterpret_cast<const ushort8v*>(Ap + k0 + 72);
      b0 = *reinterpret_cast<const ushort8v*>(Bp + k0 + 64);
      b1 = *reinterpret_cast<const ushort8v*>(Bp + k0 + 72);
    }
#pragma unroll
    for (int ks = 0; ks < 2; ++ks) {
      short8v af[2], bf2v[2];
#pragma unroll
      for (int f = 0; f < 2; ++f)
        af[f] = *reinterpret_cast<const short8v*>(&As[wr * 32 + f * 16 + lr][ks * 32 + kq * 8]);
#pragma unroll
      for (int g2 = 0; g2 < 2; ++g2)
        bf2v[g2] = *reinterpret_cast<const short8v*>(&Bs[wc * 32 + g2 * 16 + lr][ks * 32 + kq * 8]);
#pragma unroll
      for (int f = 0; f < 2; ++f)
#pragma unroll
        for (int g2 = 0; g2 < 2; ++g2)
          acc[f][g2] = __builtin_amdgcn_mfma_f32_16x16x32_bf16(af[f], bf2v[g2], acc[f][g2], 0, 0, 0);
    }
  }
#pragma unroll
  for (int f = 0; f < 2; ++f)
#pragma unroll
    for (int g2 = 0; g2 < 2; ++g2) {
      int col = n0 + wc * 32 + g2 * 16 + lr;
#pragma unroll
      for (int r = 0; r < 4; ++r) {
        int row = m0 + wr * 32 + f * 16 + kq * 4 + r;
        float v = acc[f][g2][r];
        if (EPI == 0) {
          if (resid) v += resid[(size_t)row * N + col];
          C[(size_t)row * N + col] = v;
        } else {
          int b = row >> 6;
          if (col < DI_) {
            float sv = siluf(cconv[b * DI_ + col] + v * Wc4[col * 4 + 3]);
            xcv_bf[(size_t)row * DI_ + col] = f2bf(sv);
          } else {
            zbuf[(size_t)row * DI_ + (col - DI_)] = v;
          }
        }
      }
    }
}

template<int EPI>
__global__ __launch_bounds__(256) void gemm_bf16(
    const unsigned short* __restrict__ A, const unsigned short* __restrict__ Bt,
    const float* __restrict__ resid, float* __restrict__ C, int M, int N, int K,
    const float* __restrict__ cconv, const float* __restrict__ Wc4,
    unsigned short* __restrict__ xcv_bf, float* __restrict__ zbuf)
{
  __shared__ unsigned short As[64][72];
  __shared__ unsigned short Bs[64][72];
  gemm_body<EPI>(As, Bs, blockIdx.x, blockIdx.y, A, Bt, resid, C, M, N, K,
                 cconv, Wc4, xcv_bf, zbuf);
}

// fused: phase-A in-proj (512 blocks) + phase-B in-proj EPI=1 (128 blocks)
__global__ __launch_bounds__(256) void fused_gemm_in(
    const unsigned short* __restrict__ Aa, const unsigned short* __restrict__ Bta,
    float* __restrict__ Ca,
    const unsigned short* __restrict__ Ab, const unsigned short* __restrict__ Btb,
    const float* __restrict__ cconv, const float* __restrict__ Wc4,
    unsigned short* __restrict__ xcv_bf, float* __restrict__ zbuf)
{
  __shared__ unsigned short As[64][72];
  __shared__ unsigned short Bs[64][72];
  int f = blockIdx.x;
  if (f < 512)
    gemm_body<0>(As, Bs, f & 15, f >> 4, Aa, Bta, nullptr, Ca, CTX, TWO_DI, D_,
                 nullptr, nullptr, nullptr, nullptr);
  else {
    f -= 512;
    gemm_body<1>(As, Bs, f & 15, f >> 4, Ab, Btb, nullptr, nullptr, TGT, TWO_DI, D_,
                 cconv, Wc4, xcv_bf, zbuf);
  }
}

// ------- small-tile MFMA GEMM: 32x32 tile (tgt out-proj) -------
__device__ __forceinline__ void gemm_s_body(int bx, int by,
    const unsigned short* __restrict__ A, const unsigned short* __restrict__ Bt,
    const float* __restrict__ resid, float* __restrict__ C, int M, int N, int K)
{
  __shared__ unsigned short As[32][72];
  __shared__ unsigned short Bs[32][72];
  int tid = threadIdx.x;
  int n0 = bx * 32, m0 = by * 32;
  int w = tid >> 6, lane = tid & 63;
  int lr = lane & 15, kq = lane >> 4;
  int wr = w >> 1, wc = w & 1;
  int srow = tid >> 3, schunk = (tid & 7) * 8;
  const unsigned short* Ap = &A[(size_t)(m0 + srow) * K + schunk];
  const unsigned short* Bp = &Bt[(size_t)(n0 + srow) * K + schunk];
  ushort8v a0 = *reinterpret_cast<const ushort8v*>(Ap);
  ushort8v b0 = *reinterpret_cast<const ushort8v*>(Bp);
  floatx4 acc = {};
  for (int k0 = 0; k0 < K; k0 += 64) {
    __syncthreads();
    *reinterpret_cast<ushort8v*>(&As[srow][schunk]) = a0;
    *reinterpret_cast<ushort8v*>(&Bs[srow][schunk]) = b0;
    __syncthreads();
    if (k0 + 64 < K) {
      a0 = *reinterpret_cast<const ushort8v*>(Ap + k0 + 64);
      b0 = *reinterpret_cast<const ushort8v*>(Bp + k0 + 64);
    }
#pragma unroll
    for (int ks = 0; ks < 2; ++ks) {
      short8v af = *reinterpret_cast<const short8v*>(&As[wr * 16 + lr][ks * 32 + kq * 8]);
      short8v bf = *reinterpret_cast<const short8v*>(&Bs[wc * 16 + lr][ks * 32 + kq * 8]);
      acc = __builtin_amdgcn_mfma_f32_16x16x32_bf16(af, bf, acc, 0, 0, 0);
    }
  }
  int col = n0 + wc * 16 + lr;
#pragma unroll
  for (int r = 0; r < 4; ++r) {
    int row = m0 + wr * 16 + kq * 4 + r;
    float v = acc[r];
    if (resid) v += resid[(size_t)row * N + col];
    C[(size_t)row * N + col] = v;
  }
}

__global__ __launch_bounds__(256) void gemm_s(
    const unsigned short* __restrict__ A, const unsigned short* __restrict__ Bt,
    const float* __restrict__ resid, float* __restrict__ C, int M, int N, int K)
{
  gemm_s_body(blockIdx.x, blockIdx.y, A, Bt, resid, C, M, N, K);
}

// ===== lean ctx conv: conv+silu (reg-cached taps) -> dbl (MFMA) -> dt =====
// 128 block-ids = seq*16+chunk; 16 tokens/block. No scan here.
__device__ __forceinline__ void conv_body_lean(int blk,
    const float* __restrict__ xz, const float* __restrict__ Wc,
    const float* __restrict__ bc, const unsigned short* __restrict__ Wxt,
    const float* __restrict__ WdtT, const float* __restrict__ bdt,
    unsigned short* __restrict__ xcvb, float* __restrict__ dtb,
    float* __restrict__ dblg, float* __restrict__ cconv)
{
  __shared__ unsigned short xcs[16][528];
  __shared__ float dbl_s[16][48];
  int seq = blk >> 4, ch = blk & 15;
  int tok0 = blk * 16;
  int tid = threadIdx.x;
  int base = ch * 16;
  // ---- conv + silu: tap rows cached in registers (19 loads per channel) ----
#pragma unroll
  for (int hh = 0; hh < 2; ++hh) {
    int c = tid + hh * 256;
    const float4 wv = *reinterpret_cast<const float4*>(&Wc[c * 4]);
    float bcv = bc[c];
    const float* xzs = &xz[(size_t)(seq * NC) * TWO_DI + c];
    float r[19];
#pragma unroll
    for (int i = 0; i < 19; ++i) {
      int tl = base - 3 + i;
      r[i] = (tl >= 0) ? xzs[(size_t)tl * TWO_DI] : 0.f;
    }
#pragma unroll
    for (int t = 0; t < 16; ++t) {
      float acc = bcv + r[t] * wv.x + r[t + 1] * wv.y + r[t + 2] * wv.z + r[t + 3] * wv.w;
      unsigned short sv = f2bf(siluf(acc));
      xcs[t][c] = sv;
      xcvb[(size_t)(tok0 + t) * DI_ + c] = sv;
    }
    if (ch == 15)   // conv constant for this batch's 64 decode steps (rows 253..255)
      cconv[seq * DI_ + c] = bcv + r[16] * wv.x + r[17] * wv.y + r[18] * wv.z;
  }
  __syncthreads();
  // ---- dbl[16][48] = xcv @ Wx^T via MFMA (3 waves) ----
  int w = tid >> 6, lane = tid & 63, lr = lane & 15, kq = lane >> 4;
  if (w < 3) {
    floatx4 acc = {};
#pragma unroll
    for (int kc = 0; kc < 16; ++kc) {
      short8v bb = *reinterpret_cast<const short8v*>(&Wxt[(size_t)(w * 16 + lr) * DI_ + kc * 32 + kq * 8]);
      short8v aa = *reinterpret_cast<const short8v*>(&xcs[lr][kc * 32 + kq * 8]);
      acc = __builtin_amdgcn_mfma_f32_16x16x32_bf16(aa, bb, acc, 0, 0, 0);
    }
#pragma unroll
    for (int r2 = 0; r2 < 4; ++r2) {
      int t = kq * 4 + r2, col = w * 16 + lr;
      dbl_s[t][col] = acc[r2];
      dblg[(size_t)(tok0 + t) * NDBL + col] = acc[r2];
    }
  }
  __syncthreads();
  // ---- dt = softplus(dbl[:, :16] @ Wdt + bdt), WdtT coalesced float4 ----
#pragma unroll
  for (int hh = 0; hh < 2; ++hh) {
    int c = tid + hh * 256;
    float wr_[16];
    const float4* wt4 = reinterpret_cast<const float4*>(&WdtT[c * 16]);
#pragma unroll
    for (int q = 0; q < 4; ++q) {
      float4 v4 = wt4[q];
      wr_[q * 4] = v4.x; wr_[q * 4 + 1] = v4.y; wr_[q * 4 + 2] = v4.z; wr_[q * 4 + 3] = v4.w;
    }
    float bv = bdt[c];
#pragma unroll
    for (int t = 0; t < 16; ++t) {
      float accd = bv;
#pragma unroll
      for (int r2 = 0; r2 < 16; ++r2) accd += dbl_s[t][r2] * wr_[r2];
      dtb[(size_t)(tok0 + t) * DI_ + c] = softplusf(accd);
    }
  }
}

__global__ __launch_bounds__(256) void conv_lean_kern(
    const float* __restrict__ xz, const float* __restrict__ Wc,
    const float* __restrict__ bc, const unsigned short* __restrict__ Wxt,
    const float* __restrict__ WdtT, const float* __restrict__ bdt,
    unsigned short* __restrict__ xcvb, float* __restrict__ dtb,
    float* __restrict__ dblg, float* __restrict__ cconv)
{
  conv_body_lean(blockIdx.x, xz, Wc, bc, Wxt, WdtT, bdt, xcvb, dtb, dblg, cconv);
}

// ===== pass-1 S,P: 4096 blocks = (128 chunks) x (32 dg), 16 exp/thread =====
__device__ __forceinline__ void sp_body(int b,
    const float* __restrict__ dblg, const unsigned short* __restrict__ xcvb,
    const float* __restrict__ dtb, const float* __restrict__ Aneg,
    float* __restrict__ Sb, float* __restrict__ Pb)
{
  int dg = b & 31, sc = b >> 5;
  int tid = threadIdx.x;
  int tt = tid >> 4, cc = tid & 15;
  int tok0 = sc * CLEN;
  __shared__ float dts[16][17], xs[16][17], Bs[16][17];
  dts[tt][cc] = dtb[(size_t)(tok0 + tt) * DI_ + dg * 16 + cc];
  xs[tt][cc]  = bf2f(xcvb[(size_t)(tok0 + tt) * DI_ + dg * 16 + cc]);
  Bs[tt][cc]  = dblg[(size_t)(tok0 + tt) * NDBL + RR + cc];
  __syncthreads();
  int dl = tt, n = cc;
  int d = dg * 16 + dl;
  float A = Aneg[d * NSTATE + n];
  float Bn[16];
#pragma unroll
  for (int t = 0; t < CLEN; ++t) Bn[t] = Bs[t][n];
  float h = 0.f, p = 1.f;
#pragma unroll
  for (int t = 0; t < CLEN; ++t) {
    float dtv = dts[t][dl];
    float dA  = __expf(dtv * A);
    h = fmaf(dA, h, dtv * xs[t][dl] * Bn[t]);
    p *= dA;
  }
  size_t o = ((size_t)sc * DI_ + d) * NSTATE + n;
  Sb[o] = h; Pb[o] = p;
}

__global__ __launch_bounds__(256) void sp_kern(
    const float* __restrict__ dblg, const unsigned short* __restrict__ xcvb,
    const float* __restrict__ dtb, const float* __restrict__ Aneg,
    float* __restrict__ Sb, float* __restrict__ Pb)
{
  sp_body(blockIdx.x, dblg, xcvb, dtb, Aneg, Sb, Pb);
}

// fused: B out-proj gemm_s (128 blocks first) + A sp pass (4096 blocks)
__global__ __launch_bounds__(256) void fused_sp_gout(
    const unsigned short* __restrict__ Ag, const unsigned short* __restrict__ Btg,
    const float* __restrict__ residg, float* __restrict__ Cg,
    const float* __restrict__ dblg, const unsigned short* __restrict__ xcvb,
    const float* __restrict__ dtb, const float* __restrict__ Aneg,
    float* __restrict__ Sb, float* __restrict__ Pb)
{
  if (blockIdx.x < 128) {
    int f = blockIdx.x;
    gemm_s_body(f & 7, f >> 3, Ag, Btg, residg, Cg, TGT, D_, DI_);
  } else {
    sp_body(blockIdx.x - 128, dblg, xcvb, dtb, Aneg, Sb, Pb);
  }
}

// ---- scan finalize: prefix-combine entry state, re-scan chunk, C-reduce + gate ----
__global__ __launch_bounds__(256) void scan_fin(
    const float* __restrict__ dblg, const unsigned short* __restrict__ xcvb,
    const float* __restrict__ xz, const float* __restrict__ dtb,
    const float* __restrict__ Sb, const float* __restrict__ Pb,
    const float* __restrict__ Aneg, const float* __restrict__ Dp,
    unsigned short* __restrict__ yb, float* __restrict__ hstate)
{
  int b = blockIdx.x;
  int dg = b & 31, sc = b >> 5;
  int seq = sc >> 4, chunk = sc & 15;
  int tid = threadIdx.x;
  int tt = tid >> 4, cc = tid & 15;
  int tok0 = sc * CLEN;
  __shared__ float dts[16][17], xs[16][17], zs[16][17], Bs[16][17], Cs[16][17], ys[16][17];
  dts[tt][cc] = dtb[(size_t)(tok0 + tt) * DI_ + dg * 16 + cc];
  xs[tt][cc]  = bf2f(xcvb[(size_t)(tok0 + tt) * DI_ + dg * 16 + cc]);
  zs[tt][cc]  = xz[(size_t)(tok0 + tt) * TWO_DI + DI_ + dg * 16 + cc];
  Bs[tt][cc]  = dblg[(size_t)(tok0 + tt) * NDBL + RR + cc];
  Cs[tt][cc]  = dblg[(size_t)(tok0 + tt) * NDBL + RR + NSTATE + cc];
  __syncthreads();
  int dl = tt, n = cc;
  int d = dg * 16 + dl;
  float A  = Aneg[d * NSTATE + n];
  float Dv = Dp[d];
  float Bn[16], Cn[16];                 // B/C rows for this thread's n -> registers
#pragma unroll
  for (int t = 0; t < CLEN; ++t) { Bn[t] = Bs[t][n]; Cn[t] = Cs[t][n]; }
  float h = 0.f;
  for (int c2 = 0; c2 < chunk; ++c2) {
    size_t o = ((size_t)(seq * NCHUNK + c2) * DI_ + d) * NSTATE + n;
    h = fmaf(Pb[o], h, Sb[o]);
  }
#pragma unroll
  for (int t = 0; t < CLEN; ++t) {
    float dtv = dts[t][dl];
    float xv  = xs[t][dl];
    float dA  = __expf(dtv * A);
    h = fmaf(dA, h, dtv * xv * Bn[t]);
    float p = h * Cn[t];
    p += __shfl_xor(p, 1); p += __shfl_xor(p, 2);
    p += __shfl_xor(p, 4); p += __shfl_xor(p, 8);
    if (n == 0) ys[t][dl] = (p + xv * Dv) * siluf(zs[t][dl]);
  }
  __syncthreads();
  yb[(size_t)(tok0 + tt) * DI_ + dg * 16 + cc] = f2bf(ys[tt][cc]);
  if (chunk == NCHUNK - 1)
    hstate[(size_t)seq * DI_ * NSTATE + d * NSTATE + n] = h;
}

// ---- target SSM, 256 block-ids = (32 token-groups) x (8 ch-groups of 64). ----
__device__ __forceinline__ void ssm_body(int blk,
    const unsigned short* __restrict__ xcv_bf, const float* __restrict__ zbuf,
    const unsigned short* __restrict__ Wx, const float* __restrict__ WdtT_l,
    const float* __restrict__ bdt_l, const float* __restrict__ An_l,
    const float* __restrict__ Dp_l, const float* __restrict__ hs,
    unsigned short* __restrict__ ybf)
{
  __shared__ float dbl_s[16][48];
  int tg = blk >> 3, cg = blk & 7;
  int tok0 = tg * 16;
  int b = tg >> 2;                      // batch (64 tokens each)
  int tid = threadIdx.x;
  int w = tid >> 6, lane = tid & 63, lr = lane & 15, kq = lane >> 4;
  if (w < 3) {
    floatx4 acc = {};
#pragma unroll
    for (int kc = 0; kc < 16; ++kc) {
      short8v bb = *reinterpret_cast<const short8v*>(&Wx[(size_t)(w * 16 + lr) * DI_ + kc * 32 + kq * 8]);
      short8v aa = *reinterpret_cast<const short8v*>(&xcv_bf[(size_t)(tok0 + lr) * DI_ + kc * 32 + kq * 8]);
      acc = __builtin_amdgcn_mfma_f32_16x16x32_bf16(aa, bb, acc, 0, 0, 0);
    }
#pragma unroll
    for (int r = 0; r < 4; ++r)
      dbl_s[kq * 4 + r][w * 16 + lr] = acc[r];
  }
  __syncthreads();
  int c = cg * 64 + (tid & 63);
  int t0 = (tid >> 6) * 4;              // 4 tokens per thread
  float wdt_r[16], An[16], hr[16];
  const float4* wt4 = reinterpret_cast<const float4*>(&WdtT_l[c * 16]);
  const float4* An4 = reinterpret_cast<const float4*>(&An_l[c * NSTATE]);
  const float4* hr4 = reinterpret_cast<const float4*>(&hs[(size_t)b * DI_ * NSTATE + c * NSTATE]);
#pragma unroll
  for (int q = 0; q < 4; ++q) {
    float4 wv = wt4[q]; wdt_r[q*4]=wv.x; wdt_r[q*4+1]=wv.y; wdt_r[q*4+2]=wv.z; wdt_r[q*4+3]=wv.w;
    float4 a = An4[q]; An[q*4]=a.x; An[q*4+1]=a.y; An[q*4+2]=a.z; An[q*4+3]=a.w;
    float4 hv = hr4[q]; hr[q*4]=hv.x; hr[q*4+1]=hv.y; hr[q*4+2]=hv.z; hr[q*4+3]=hv.w;
  }
  float Dv = Dp_l[c], bv = bdt_l[c];
#pragma unroll
  for (int tt = 0; tt < 4; ++tt) {
    int t = t0 + tt;
    float accd = bv;
#pragma unroll
    for (int r = 0; r < 16; ++r) accd += dbl_s[t][r] * wdt_r[r];
    float dtv = softplusf(accd);
    float xv = bf2f(xcv_bf[(size_t)(tok0 + t) * DI_ + c]);
    float coef = dtv * xv;
    float y = 0.f;
#pragma unroll
    for (int n = 0; n < 16; ++n) {
      float hn = fmaf(__expf(dtv * An[n]), hr[n], coef * dbl_s[t][RR + n]);
      y = fmaf(hn, dbl_s[t][RR + NSTATE + n], y);
    }
    float yv = (y + xv * Dv) * siluf(zbuf[(size_t)(tok0 + t) * DI_ + c]);
    ybf[(size_t)(tok0 + t) * DI_ + c] = f2bf(yv);
  }
}

__global__ __launch_bounds__(256) void tgt_ssm2(
    const unsigned short* __restrict__ xcv_bf, const float* __restrict__ zbuf,
    const unsigned short* __restrict__ Wx, const float* __restrict__ WdtT_l,
    const float* __restrict__ bdt_l, const float* __restrict__ An_l,
    const float* __restrict__ Dp_l, const float* __restrict__ hs,
    unsigned short* __restrict__ ybf)
{
  ssm_body(blockIdx.x, xcv_bf, zbuf, Wx, WdtT_l, bdt_l, An_l, Dp_l, hs, ybf);
}

// fused: lean conv for A layer (128 blocks) + tgt SSM for B layer (256 blocks)
__global__ __launch_bounds__(256) void fused_conv_ssm(
    const float* __restrict__ xz, const float* __restrict__ Wc,
    const float* __restrict__ bc, const unsigned short* __restrict__ WxtA,
    const float* __restrict__ WdtTA, const float* __restrict__ bdtA,
    unsigned short* __restrict__ xcvb, float* __restrict__ dtb,
    float* __restrict__ dblg, float* __restrict__ cconv,
    const unsigned short* __restrict__ xcv_bfB, const float* __restrict__ zbufB,
    const unsigned short* __restrict__ WxB, const float* __restrict__ WdtTB,
    const float* __restrict__ bdtB, const float* __restrict__ AnB,
    const float* __restrict__ DpB, const float* __restrict__ hsB,
    unsigned short* __restrict__ ybfB)
{
  if (blockIdx.x < BSEQ * NCHUNK)
    conv_body_lean(blockIdx.x, xz, Wc, bc, WxtA, WdtTA, bdtA,
                   xcvb, dtb, dblg, cconv);
  else
    ssm_body(blockIdx.x - BSEQ * NCHUNK, xcv_bfB, zbufB, WxB, WdtTB, bdtB,
             AnB, DpB, hsB, ybfB);
}

extern "C" void kernel_launch(void* const* d_in, const int* in_sizes, int n_in,
                              void* d_out, int out_size, void* d_ws, size_t ws_size,
                              hipStream_t stream)
{
  const float* xc   = (const float*)d_in[0];
  const float* xt   = (const float*)d_in[1];
  const float* ln_g = (const float*)d_in[2];
  const float* ln_b = (const float*)d_in[3];
  const float* W_in = (const float*)d_in[4];
  const float* W_cv = (const float*)d_in[5];
  const float* b_cv = (const float*)d_in[6];
  const float* W_x  = (const float*)d_in[7];
  const float* W_dt = (const float*)d_in[8];
  const float* b_dt = (const float*)d_in[9];
  const float* Alog = (const float*)d_in[10];
  const float* Dp   = (const float*)d_in[11];
  const float* W_o  = (const float*)d_in[12];
  float* out = (float*)d_out;

  float* ws = (float*)d_ws;
  size_t off = 0;
  auto alloc = [&](size_t n) { float* p = ws + off; off += n; return p; };
  float* xz     = alloc((size_t)CTX * TWO_DI);
  float* dtb    = alloc((size_t)CTX * DI_);
  float* dblg   = alloc((size_t)CTX * NDBL);
  float* xcur   = alloc((size_t)CTX * D_);
  float* Sb     = alloc((size_t)BSEQ * NCHUNK * DI_ * NSTATE);
  float* Pb     = alloc((size_t)BSEQ * NCHUNK * DI_ * NSTATE);
  float* cconvT = alloc((size_t)4 * BSEQ * DI_);
  float* hst    = alloc((size_t)4 * BSEQ * DI_ * NSTATE);
  float* Aneg   = alloc((size_t)4 * DI_ * NSTATE);
  float* WdtT   = alloc((size_t)4 * DI_ * RR);
  float* zbufB  = alloc((size_t)TGT * DI_);
  float* xtb    = alloc((size_t)TGT * D_);
  unsigned short* hbuf_bf = (unsigned short*)alloc((size_t)CTX * D_ / 2);
  unsigned short* hbufB   = (unsigned short*)alloc((size_t)TGT * D_ / 2);
  unsigned short* xcvb    = (unsigned short*)alloc((size_t)CTX * DI_ / 2);
  unsigned short* yb_bf   = (unsigned short*)alloc((size_t)CTX * DI_ / 2);
  unsigned short* xcv_bfB = (unsigned short*)alloc((size_t)TGT * DI_ / 2);
  unsigned short* y_bfB   = (unsigned short*)alloc((size_t)TGT * DI_ / 2);
  unsigned short* Wint    = (unsigned short*)alloc((size_t)4 * TWO_DI * D_ / 2);
  unsigned short* Wot     = (unsigned short*)alloc((size_t)4 * D_ * DI_ / 2);
  unsigned short* Wxt     = (unsigned short*)alloc((size_t)4 * NDBL * DI_ / 2);
  if (off * sizeof(float) > ws_size) return;

  prep_all<<<1920, 256, 0, stream>>>(W_in, W_o, W_x, Alog, W_dt,
                                     Wint, Wot, Wxt, Aneg, WdtT);

  // -------- A0 (no B partner yet) --------
  ln_kern<<<CTX / 4, 256, 0, stream>>>(xc, ln_g, ln_b, hbuf_bf, CTX);
  gemm_bf16<0><<<dim3(TWO_DI / 64, CTX / 64), 256, 0, stream>>>(
      hbuf_bf, Wint, nullptr, xz, CTX, TWO_DI, D_, nullptr, nullptr, nullptr, nullptr);
  conv_lean_kern<<<BSEQ * NCHUNK, 256, 0, stream>>>(
      xz, W_cv, b_cv, Wxt, WdtT, b_dt, xcvb, dtb, dblg, cconvT);
  sp_kern<<<BSEQ * NCHUNK * 32, 256, 0, stream>>>(dblg, xcvb, dtb, Aneg, Sb, Pb);
  scan_fin<<<BSEQ * NCHUNK * 32, 256, 0, stream>>>(
      dblg, xcvb, xz, dtb, Sb, Pb, Aneg, Dp, yb_bf, hst);
  gemm_bf16<0><<<dim3(D_ / 64, CTX / 64), 256, 0, stream>>>(
      yb_bf, Wot, xc, xcur, CTX, D_, DI_, nullptr, nullptr, nullptr, nullptr);

  // -------- groups: A(l+1) co-scheduled with B(l) --------
  for (int l = 0; l < 3; ++l) {
    int la = l + 1;
    const float* xinB = (l == 0) ? xt : xtb;
    fused_ln<<<CTX / 4 + TGT / 4, 256, 0, stream>>>(
        xcur, ln_g + la * D_, ln_b + la * D_, hbuf_bf,
        xinB, ln_g + l * D_,  ln_b + l * D_,  hbufB);
    fused_gemm_in<<<512 + 128, 256, 0, stream>>>(
        hbuf_bf, Wint + (size_t)la * TWO_DI * D_, xz,
        hbufB,   Wint + (size_t)l * TWO_DI * D_,
        cconvT + (size_t)l * BSEQ * DI_, W_cv + l * DI_ * 4, xcv_bfB, zbufB);
    fused_conv_ssm<<<BSEQ * NCHUNK + 256, 256, 0, stream>>>(
        xz, W_cv + la * DI_ * 4, b_cv + la * DI_, Wxt + (size_t)la * NDBL * DI_,
        WdtT + (size_t)la * DI_ * RR, b_dt + la * DI_,
        xcvb, dtb, dblg, cconvT + (size_t)la * BSEQ * DI_,
        xcv_bfB, zbufB, Wxt + (size_t)l * NDBL * DI_, WdtT + (size_t)l * DI_ * RR,
        b_dt + l * DI_, Aneg + l * DI_ * NSTATE, Dp + l * DI_,
        hst + (size_t)l * BSEQ * DI_ * NSTATE, y_bfB);
    fused_sp_gout<<<128 + BSEQ * NCHUNK * 32, 256, 0, stream>>>(
        y_bfB, Wot + (size_t)l * D_ * DI_, xinB, xtb,
        dblg, xcvb, dtb, Aneg + la * DI_ * NSTATE, Sb, Pb);
    scan_fin<<<BSEQ * NCHUNK * 32, 256, 0, stream>>>(
        dblg, xcvb, xz, dtb, Sb, Pb, Aneg + la * DI_ * NSTATE, Dp + la * DI_,
        yb_bf, hst + (size_t)la * BSEQ * DI_ * NSTATE);
    if (la < 3)
      gemm_bf16<0><<<dim3(D_ / 64, CTX / 64), 256, 0, stream>>>(
          yb_bf, Wot + (size_t)la * D_ * DI_, xcur, xcur, CTX, D_, DI_,
          nullptr, nullptr, nullptr, nullptr);
  }

  // -------- B3 tail --------
  ln_kern<<<TGT / 4, 256, 0, stream>>>(xtb, ln_g + 3 * D_, ln_b + 3 * D_, hbufB, TGT);
  gemm_bf16<1><<<dim3(TWO_DI / 64, TGT / 64), 256, 0, stream>>>(
      hbufB, Wint + (size_t)3 * TWO_DI * D_, nullptr, nullptr, TGT, TWO_DI, D_,
      cconvT + (size_t)3 * BSEQ * DI_, W_cv + 3 * DI_ * 4, xcv_bfB, zbufB);
  tgt_ssm2<<<256, 256, 0, stream>>>(xcv_bfB, zbufB,
      Wxt + (size_t)3 * NDBL * DI_, WdtT + (size_t)3 * DI_ * RR, b_dt + 3 * DI_,
      Aneg + 3 * DI_ * NSTATE, Dp + 3 * DI_,
      hst + (size_t)3 * BSEQ * DI_ * NSTATE, y_bfB);
  gemm_s<<<dim3(D_ / 32, TGT / 32), 256, 0, stream>>>(
      y_bfB, Wot + (size_t)3 * D_ * DI_, xtb, out, TGT, D_, DI_);
}